// Round 8
// baseline (337.069 us; speedup 1.0000x reference)
//
#include <hip/hip_runtime.h>
#include <hip/hip_bf16.h>
#include <cstdint>
#include <cstddef>

using bf16 = __hip_bfloat16;
typedef __attribute__((ext_vector_type(8))) short bf16x8;   // 8 bf16 (MFMA A/B frag)
typedef __attribute__((ext_vector_type(4))) float f32x4;    // 16x16 MFMA C/D frag
typedef __attribute__((ext_vector_type(16))) float f32x16;  // 32x32 MFMA C/D frag
typedef __attribute__((ext_vector_type(8))) _Float16 f16x8; // 8 fp16

#define B_    4
#define LQ_   1024
#define LKV_  2048
#define QDIM_ 1024
#define KDIM_ 768
#define ODIM_ 1024
#define H_    16
#define HD_   64

// ---------------------------------------------------------------------------
// async global -> LDS, 16B per lane (wave-uniform LDS base + lane*16)
// ---------------------------------------------------------------------------
__device__ __forceinline__ void async_cp16(const void* g, void* l) {
  __builtin_amdgcn_global_load_lds(
      (const __attribute__((address_space(1))) void*)g,
      (__attribute__((address_space(3))) void*)l, 16, 0, 0);
}

// pack two f32 -> one u32 of 2 bf16 (lo = a, hi = b)
__device__ __forceinline__ unsigned cvtpk(float a, float b) {
  unsigned r;
  asm("v_cvt_pk_bf16_f32 %0, %1, %2" : "=v"(r) : "v"(a), "v"(b));
  return r;
}

__device__ __forceinline__ float fast_exp2(float x) {
#if __has_builtin(__builtin_amdgcn_exp2f)
  return __builtin_amdgcn_exp2f(x);
#else
  return exp2f(x);
#endif
}

__device__ __forceinline__ bf16x8 make_frag(unsigned w0, unsigned w1,
                                            unsigned w2, unsigned w3) {
  union { unsigned u[4]; bf16x8 v; } u;
  u.u[0] = w0; u.u[1] = w1; u.u[2] = w2; u.u[3] = w3;
  return u.v;
}

// ---------------------------------------------------------------------------
// mask normalize (parallel): 1-byte bool or int32 0/1 -> float 1.0=keep/0.0=mask
// ---------------------------------------------------------------------------
__global__ void mask_prep(const void* __restrict__ mraw,
                          float* __restrict__ mf, int n) {
  const int tid = threadIdx.x;
  const unsigned char* bb = (const unsigned char*)mraw;
  int local = 0;
  for (int i = tid; i < n; i += 256)
    if ((i & 3) != 0 && bb[i] != 0) local = 1;
  __shared__ int f;
  if (tid == 0) f = 0;
  __syncthreads();
  if (__any(local) && (tid & 63) == 0) atomicOr(&f, 1);
  __syncthreads();
  const int is8 = f;
  const int* w = (const int*)mraw;
  for (int i = blockIdx.x * 256 + tid; i < n; i += gridDim.x * 256)
    mf[i] = (is8 ? (int)bb[i] : (w[i] != 0)) ? 0.f : 1.f;
}

// ---------------------------------------------------------------------------
// fused fp32 -> bf16 convert for query/key/value (blockIdx.y selects tensor)
// ---------------------------------------------------------------------------
struct alignas(8) bf4 { bf16 x[4]; };

__global__ void cvt3(const float* __restrict__ q, const float* __restrict__ k,
                     const float* __restrict__ v, bf16* __restrict__ qb,
                     bf16* __restrict__ kb, bf16* __restrict__ vb) {
  const int z = blockIdx.y;
  const float* src = (z == 0) ? q : (z == 1) ? k : v;
  bf16* dst = (z == 0) ? qb : (z == 1) ? kb : vb;
  const int n4 = (z == 0) ? (B_ * LQ_ * QDIM_) / 4 : (B_ * LKV_ * KDIM_) / 4;
  const int i = blockIdx.x * 256 + threadIdx.x;
  if (i >= n4) return;
  float4 val = reinterpret_cast<const float4*>(src)[i];
  bf4 r;
  r.x[0] = __float2bfloat16(val.x);
  r.x[1] = __float2bfloat16(val.y);
  r.x[2] = __float2bfloat16(val.z);
  r.x[3] = __float2bfloat16(val.w);
  *reinterpret_cast<bf4*>(dst + (size_t)i * 4) = r;
}

// ---------------------------------------------------------------------------
// fused weight transpose + convert: W [K][1024] fp32 -> WT [1024][K] bf16, z=4
// ---------------------------------------------------------------------------
__global__ void wtrans4(const float* __restrict__ Wq, const float* __restrict__ Wk,
                        const float* __restrict__ Wv, const float* __restrict__ Wo,
                        bf16* __restrict__ WqT, bf16* __restrict__ WkT,
                        bf16* __restrict__ WvT, bf16* __restrict__ WoT) {
  const int z = blockIdx.z;
  const float* W = (z == 0) ? Wq : (z == 1) ? Wk : (z == 2) ? Wv : Wo;
  bf16* WT = (z == 0) ? WqT : (z == 1) ? WkT : (z == 2) ? WvT : WoT;
  const int K = (z == 1 || z == 2) ? KDIM_ : ODIM_;
  const int N = ODIM_;
  const int n0 = blockIdx.x * 64, k0 = blockIdx.y * 64;
  if (k0 >= K) return;
  __shared__ bf16 t[64][65];
  const int tid = threadIdx.x;
#pragma unroll
  for (int i = 0; i < 16; ++i) {
    int idx = tid + i * 256;
    int nn = idx & 63, kk = idx >> 6;
    t[kk][nn] = __float2bfloat16(W[(size_t)(k0 + kk) * N + n0 + nn]);
  }
  __syncthreads();
#pragma unroll
  for (int i = 0; i < 16; ++i) {
    int idx = tid + i * 256;
    int kk = idx & 63, nn = idx >> 6;
    WT[(size_t)(n0 + nn) * K + k0 + kk] = t[kk][nn];
  }
}

// ---------------------------------------------------------------------------
// V transpose: vp [B][LKV][ODIM] bf16 -> vT [B][H][HD][LKV] bf16
// ---------------------------------------------------------------------------
__global__ void vtrans(const bf16* __restrict__ vp, bf16* __restrict__ vT) {
  __shared__ bf16 t[64][65];
  const int kv0 = blockIdx.x * 64, h = blockIdx.y, b = blockIdx.z;
  const int tid = threadIdx.x;
#pragma unroll
  for (int i = 0; i < 16; ++i) {
    int idx = tid + i * 256;
    int hd = idx & 63, kv = idx >> 6;
    t[kv][hd] = vp[(size_t)(b * LKV_ + kv0 + kv) * ODIM_ + h * HD_ + hd];
  }
  __syncthreads();
#pragma unroll
  for (int i = 0; i < 16; ++i) {
    int idx = tid + i * 256;
    int kv = idx & 63, nn = idx >> 6;
    vT[(size_t)((b * H_ + h) * HD_ + nn) * LKV_ + kv0 + kv] = t[kv][nn];
  }
}

// ---------------------------------------------------------------------------
// GEMM body: C[M][N] = A[M][K] @ BT[N][K]^T + bias (m97 structure)
// ---------------------------------------------------------------------------
template <int OUT_BF16>
__device__ __forceinline__ void gemm_body(const bf16* __restrict__ A,
                                          const bf16* __restrict__ BT,
                                          const float* __restrict__ bias,
                                          void* __restrict__ Cout,
                                          int M, int N, int K, int m0, int n0) {
  __shared__ bf16 As[128 * 64];
  __shared__ bf16 Bs[128 * 64];
  const int tid = threadIdx.x;
  const int lane = tid & 63, w = tid >> 6;
  const int wr = w >> 1, wc = w & 1;
  const int lr = lane & 15, lk = lane >> 4;

  f32x4 acc[4][4];
#pragma unroll
  for (int m = 0; m < 4; ++m)
#pragma unroll
    for (int n = 0; n < 4; ++n) acc[m][n] = (f32x4){0.f, 0.f, 0.f, 0.f};

  const int nk = K >> 6;
  for (int kt = 0; kt < nk; ++kt) {
    const int k0 = kt << 6;
#pragma unroll
    for (int i = 0; i < 4; ++i) {
      const int c = tid + i * 256;
      const int row = c >> 3, cc = c & 7;
      const int sc = cc ^ (row & 7);
      async_cp16(A + (size_t)(m0 + row) * K + k0 + sc * 8, As + c * 8);
    }
#pragma unroll
    for (int i = 0; i < 4; ++i) {
      const int c = tid + i * 256;
      const int row = c >> 3, cc = c & 7;
      const int sc = cc ^ (row & 7);
      async_cp16(BT + (size_t)(n0 + row) * K + k0 + sc * 8, Bs + c * 8);
    }
    asm volatile("s_waitcnt vmcnt(0)" ::: "memory");
    __syncthreads();

    bf16x8 af[4][2], bfr[4][2];
#pragma unroll
    for (int m = 0; m < 4; ++m)
#pragma unroll
      for (int ks = 0; ks < 2; ++ks) {
        const int r = wr * 64 + m * 16 + lr;
        af[m][ks] = *(const bf16x8*)((const char*)As + r * 128 +
                                     ((ks * 64 + lk * 16) ^ ((r & 7) << 4)));
      }
#pragma unroll
    for (int n = 0; n < 4; ++n)
#pragma unroll
      for (int ks = 0; ks < 2; ++ks) {
        const int r = wc * 64 + n * 16 + lr;
        bfr[n][ks] = *(const bf16x8*)((const char*)Bs + r * 128 +
                                      ((ks * 64 + lk * 16) ^ ((r & 7) << 4)));
      }
    __builtin_amdgcn_s_setprio(1);
#pragma unroll
    for (int m = 0; m < 4; ++m)
#pragma unroll
      for (int n = 0; n < 4; ++n)
#pragma unroll
        for (int ks = 0; ks < 2; ++ks)
          acc[m][n] = __builtin_amdgcn_mfma_f32_16x16x32_bf16(
              af[m][ks], bfr[n][ks], acc[m][n], 0, 0, 0);
    __builtin_amdgcn_s_setprio(0);
    __syncthreads();
  }

#pragma unroll
  for (int m = 0; m < 4; ++m)
#pragma unroll
    for (int n = 0; n < 4; ++n)
#pragma unroll
      for (int r4 = 0; r4 < 4; ++r4) {
        const int row = m0 + wr * 64 + m * 16 + lk * 4 + r4;
        const int col = n0 + wc * 64 + n * 16 + lr;
        float v = acc[m][n][r4] + bias[col];
        if (OUT_BF16)
          ((bf16*)Cout)[(size_t)row * N + col] = __float2bfloat16(v);
        else
          ((float*)Cout)[(size_t)row * N + col] = v;
      }
}

template <int OUT_BF16>
__launch_bounds__(256, 3)
__global__ void gemm_bt(const bf16* __restrict__ A, const bf16* __restrict__ BT,
                        const float* __restrict__ bias, void* __restrict__ Cout,
                        int M, int N, int K) {
  gemm_body<OUT_BF16>(A, BT, bias, Cout, M, N, K, blockIdx.y * 128,
                      blockIdx.x * 128);
}

// fused Q/K/V projection: blockIdx.z selects the GEMM
__launch_bounds__(256, 3)
__global__ void gemm_qkv(const bf16* __restrict__ qb, const bf16* __restrict__ kb,
                         const bf16* __restrict__ vb, const bf16* __restrict__ WqT,
                         const bf16* __restrict__ WkT, const bf16* __restrict__ WvT,
                         const float* __restrict__ bq, const float* __restrict__ bk,
                         const float* __restrict__ bv, bf16* __restrict__ qp,
                         bf16* __restrict__ kp, bf16* __restrict__ vp) {
  const int z = blockIdx.z;
  const bf16* A = (z == 0) ? qb : (z == 1) ? kb : vb;
  const bf16* BT = (z == 0) ? WqT : (z == 1) ? WkT : WvT;
  const float* bias = (z == 0) ? bq : (z == 1) ? bk : bv;
  bf16* C = (z == 0) ? qp : (z == 1) ? kp : vp;
  const int M = (z == 0) ? (B_ * LQ_) : (B_ * LKV_);
  const int K = (z == 0) ? QDIM_ : KDIM_;
  const int m0 = blockIdx.y * 128;
  if (m0 >= M) return;
  gemm_body<1>(A, BT, bias, C, M, ODIM_, K, m0, blockIdx.x * 128);
}

// ---------------------------------------------------------------------------
// Flash attention v6: attn5 core (sigma-permuted K, LDS dbuf K/V via
// global_load_lds, counted vmcnt, in-register softmax) + 2-WAY KV-SPLIT:
// grid 1024 blocks (d>>9 = split, d&511 = (b,h,qt) XCD-chunked as before, so
// both splits of a pair land on the same XCD). LDS 36KB -> 4 blocks/CU = 16
// waves/CU (2x the wave pool; softmax VALU overlaps MFMA across waves).
// Partials: O normalized by own l_s, stored fp16; weight w = m + log2(l).
// ---------------------------------------------------------------------------
__launch_bounds__(256, 4)
__global__ void attn6(const bf16* __restrict__ qp, const bf16* __restrict__ kp,
                      const bf16* __restrict__ vT, const float* __restrict__ mf,
                      _Float16* __restrict__ Op, float* __restrict__ Wp) {
  __shared__ bf16 Ks[2][64 * 64];   // [buf][kv][hd] swizzled, 8KB each
  __shared__ bf16 Vs[2][64 * 64];   // [buf][hd][kv] swizzled, 8KB each
  __shared__ float Ms[1024];        // mask half-row for this split, 4KB
  const int tid = threadIdx.x;
  const int w = tid >> 6, l = tid & 63;
  const int l31 = l & 31, hi = l >> 5;
  const int d = blockIdx.x;
  const int s = d >> 9, e = d & 511;
  const int hb = (e & 7) * 8 + ((e >> 3) & 7);  // XCD-chunked (b,h)
  const int qt = e >> 6;
  const int h = hb & 15, b = hb >> 4;
  const int q0 = qt * 128 + w * 32;
  const int kvbase = s * 1024;

  // sigma: A-row m (=l31) reads LDS K row sigma(m)
  const int rr = (l31 & 3) + 4 * (l31 >> 3);
  const int hh = (l31 >> 2) & 1;
  const int sig = (rr < 8) ? (8 * hh + rr) : (8 + 8 * hh + rr);

  // stage mask half-row (1024 floats, 4KB): 1 x 16B per thread
  async_cp16(mf + b * LKV_ + kvbase + tid * 4, &Ms[tid * 4]);

  // Q fragments (B-operand): lane holds Q[q0+l31][hd = ks*16 + hi*8 + j]
  bf16x8 qf[4];
  {
    const bf16* qbp =
        qp + (size_t)(b * LQ_ + q0 + l31) * ODIM_ + h * HD_ + hi * 8;
#pragma unroll
    for (int ks = 0; ks < 4; ++ks) qf[ks] = *(const bf16x8*)(qbp + ks * 16);
  }

  const int NT = 16;  // tiles of 64 kv in this split
  auto stage = [&](int t, int buf) {
    const int kv0 = kvbase + (t & (NT - 1)) * 64;
#pragma unroll
    for (int i = 0; i < 2; ++i) {
      const int c = tid + i * 256;
      const int row = c >> 3, cc = c & 7, sc = cc ^ (row & 7);
      async_cp16(kp + (size_t)(b * LKV_ + kv0 + row) * ODIM_ + h * HD_ + sc * 8,
                 &Ks[buf][c * 8]);
    }
#pragma unroll
    for (int i = 0; i < 2; ++i) {
      const int c = tid + i * 256;
      const int row = c >> 3, cc = c & 7, sc = cc ^ (row & 7);
      async_cp16(vT + (size_t)((b * H_ + h) * HD_ + row) * LKV_ + kv0 + sc * 8,
                 &Vs[buf][c * 8]);
    }
  };

  f32x16 oacc0, oacc1;
#pragma unroll
  for (int r = 0; r < 16; ++r) { oacc0[r] = 0.f; oacc1[r] = 0.f; }
  float m_ = -1e30f, l_ = 0.f;
  const float csc = 0.125f * 1.4426950408889634f;  // scale * log2(e)

  stage(0, 0);
  for (int t = 0; t < NT; ++t) {
    const int buf = t & 1;
    stage(t + 1, buf ^ 1);
    asm volatile("s_waitcnt vmcnt(4)" ::: "memory");  // own tile-t loads done
    __syncthreads();                                  // whole tile t in LDS

    // ---- QK^T from LDS (rows sig / sig+32, chunk = ks*2+hi, XOR swizzle)
    f32x16 s0, s1;
#pragma unroll
    for (int r = 0; r < 16; ++r) { s0[r] = 0.f; s1[r] = 0.f; }
    __builtin_amdgcn_s_setprio(1);
#pragma unroll
    for (int ks = 0; ks < 4; ++ks) {
      const int ch = ks * 2 + hi;
      bf16x8 k0 = *(const bf16x8*)((const char*)&Ks[buf][0] + sig * 128 +
                                   ((ch ^ (sig & 7)) * 16));
      const int s2 = sig + 32;
      bf16x8 k1 = *(const bf16x8*)((const char*)&Ks[buf][0] + s2 * 128 +
                                   ((ch ^ (s2 & 7)) * 16));
      s0 = __builtin_amdgcn_mfma_f32_32x32x16_bf16(k0, qf[ks], s0, 0, 0, 0);
      s1 = __builtin_amdgcn_mfma_f32_32x32x16_bf16(k1, qf[ks], s1, 0, 0, 0);
    }
    __builtin_amdgcn_s_setprio(0);

    // ---- mask multipliers from LDS (broadcast reads)
    const int mb = t * 64 + hi * 8;
    f32x4 mq0[4], mq1[4];
    mq0[0] = *(const f32x4*)&Ms[mb + 0];
    mq0[1] = *(const f32x4*)&Ms[mb + 4];
    mq0[2] = *(const f32x4*)&Ms[mb + 16];
    mq0[3] = *(const f32x4*)&Ms[mb + 20];
    mq1[0] = *(const f32x4*)&Ms[mb + 32];
    mq1[1] = *(const f32x4*)&Ms[mb + 36];
    mq1[2] = *(const f32x4*)&Ms[mb + 48];
    mq1[3] = *(const f32x4*)&Ms[mb + 52];

    // ---- row max over the 64 kv of this tile (order-agnostic)
    float rm = s0[0];
#pragma unroll
    for (int r = 1; r < 16; ++r) rm = fmaxf(rm, s0[r]);
#pragma unroll
    for (int r = 0; r < 16; ++r) rm = fmaxf(rm, s1[r]);
    rm = fmaxf(rm, __shfl_xor(rm, 32));
    const float pm = rm * csc;

    // ---- defer-max rescale (rare; wave-uniform branch)
    if (__any(pm > m_ + 11.0f)) {
      const float mn = fmaxf(m_, pm);
      const float alpha = fast_exp2(m_ - mn);
      l_ *= alpha;
      m_ = mn;
#pragma unroll
      for (int r = 0; r < 16; ++r) {
        const float av = __shfl(alpha, (r & 3) + 8 * (r >> 2) + 4 * hi);
        oacc0[r] *= av;
        oacc1[r] *= av;
      }
    }

    // ---- p = 2^(s*c - m) * mask ; row sum
    float psum = 0.f;
#pragma unroll
    for (int r = 0; r < 16; ++r) {
      float p0 = fast_exp2(fmaf(s0[r], csc, -m_)) * mq0[r >> 2][r & 3];
      float p1 = fast_exp2(fmaf(s1[r], csc, -m_)) * mq1[r >> 2][r & 3];
      s0[r] = p0;
      s1[r] = p1;
      psum += p0 + p1;
    }
    psum += __shfl_xor(psum, 32);
    l_ += psum;

    // ---- pack P into PV A-frags: pure lane-local cvt_pk
    bf16x8 pa[4];
    pa[0] = make_frag(cvtpk(s0[0], s0[1]), cvtpk(s0[2], s0[3]),
                      cvtpk(s0[4], s0[5]), cvtpk(s0[6], s0[7]));
    pa[1] = make_frag(cvtpk(s0[8], s0[9]), cvtpk(s0[10], s0[11]),
                      cvtpk(s0[12], s0[13]), cvtpk(s0[14], s0[15]));
    pa[2] = make_frag(cvtpk(s1[0], s1[1]), cvtpk(s1[2], s1[3]),
                      cvtpk(s1[4], s1[5]), cvtpk(s1[6], s1[7]));
    pa[3] = make_frag(cvtpk(s1[8], s1[9]), cvtpk(s1[10], s1[11]),
                      cvtpk(s1[12], s1[13]), cvtpk(s1[14], s1[15]));

    // ---- O += P @ V from LDS (rows l31 / l31+32)
    __builtin_amdgcn_s_setprio(1);
#pragma unroll
    for (int ks = 0; ks < 4; ++ks) {
      const int ch = ks * 2 + hi;
      bf16x8 v0 = *(const bf16x8*)((const char*)&Vs[buf][0] + l31 * 128 +
                                   ((ch ^ (l31 & 7)) * 16));
      const int r2 = l31 + 32;
      bf16x8 v1 = *(const bf16x8*)((const char*)&Vs[buf][0] + r2 * 128 +
                                   ((ch ^ (r2 & 7)) * 16));
      oacc0 = __builtin_amdgcn_mfma_f32_32x32x16_bf16(pa[ks], v0, oacc0, 0, 0, 0);
      oacc1 = __builtin_amdgcn_mfma_f32_32x32x16_bf16(pa[ks], v1, oacc1, 0, 0, 0);
    }
    __builtin_amdgcn_s_setprio(0);
    __syncthreads();  // all waves done reading buf before it is restaged
  }

  // ---- epilogue: normalized fp16 partials + log2-domain weight
  const float linv = (l_ > 0.f) ? (1.0f / l_) : 0.f;
  const float wv = (l_ > 0.f) ? (m_ + __log2f(l_)) : -1e30f;
  if (hi == 0) Wp[((size_t)d * 4 + w) * 32 + l31] = wv;
  _Float16* ob = Op + (size_t)d * 32768 + w * 32 * 64;
#pragma unroll
  for (int r = 0; r < 16; ++r) {
    const int cr = (r & 3) + 8 * (r >> 2) + 4 * hi;
    const float lv = __shfl(linv, cr);
    ob[cr * 64 + l31] = (_Float16)(oacc0[r] * lv);
    ob[cr * 64 + 32 + l31] = (_Float16)(oacc1[r] * lv);
  }
}

// ---------------------------------------------------------------------------
// combine: att[q][hd] = (c0*O0 + c1*O1)/(c0+c1), c_s = 2^(w_s - max w)
// grid 512 (= e), 256 thr; thread -> q = tid>>1, hd half = (tid&1)*32.
// ---------------------------------------------------------------------------
__global__ void attn_combine(const _Float16* __restrict__ Op,
                             const float* __restrict__ Wp,
                             bf16* __restrict__ att) {
  const int e = blockIdx.x, tid = threadIdx.x;
  const int q = tid >> 1, hd0 = (tid & 1) * 32;
  const int hb = (e & 7) * 8 + ((e >> 3) & 7);
  const int qt = e >> 6;
  const int h = hb & 15, b = hb >> 4;
  const float w0 = Wp[(size_t)e * 128 + q];
  const float w1 = Wp[(size_t)(512 + e) * 128 + q];
  const float mw = fmaxf(w0, w1);
  const float c0 = fast_exp2(w0 - mw), c1 = fast_exp2(w1 - mw);
  const float inv = 1.0f / (c0 + c1);
  const float a0 = c0 * inv, a1 = c1 * inv;
  const _Float16* p0 = Op + (size_t)e * 32768 + q * 64 + hd0;
  const _Float16* p1 = p0 + (size_t)512 * 32768;
  bf16* ob = att + (size_t)(b * LQ_ + qt * 128 + q) * ODIM_ + h * HD_ + hd0;
#pragma unroll
  for (int c = 0; c < 4; ++c) {
    f16x8 v0 = *(const f16x8*)(p0 + c * 8);
    f16x8 v1 = *(const f16x8*)(p1 + c * 8);
    bf4 r0;
#pragma unroll
    for (int j = 0; j < 8; j += 2) {
      r0.x[j & 3] = __float2bfloat16((float)v0[j] * a0 + (float)v1[j] * a1);
      r0.x[(j + 1) & 3] = __float2bfloat16((float)v0[j + 1] * a0 + (float)v1[j + 1] * a1);
      if ((j & 3) == 2) *reinterpret_cast<bf4*>(ob + c * 8 + (j > 3 ? 4 : 0)) = r0;
    }
  }
}

// ---------------------------------------------------------------------------
extern "C" void kernel_launch(void* const* d_in, const int* in_sizes, int n_in,
                              void* d_out, int out_size, void* d_ws,
                              size_t ws_size, hipStream_t stream) {
  const float* query = (const float*)d_in[0];
  const float* key   = (const float*)d_in[1];
  const float* value = (const float*)d_in[2];
  const void* mask_raw = d_in[3];
  const float* Wq = (const float*)d_in[4];
  const float* bq = (const float*)d_in[5];
  const float* Wk = (const float*)d_in[6];
  const float* bk = (const float*)d_in[7];
  const float* Wv = (const float*)d_in[8];
  const float* bv = (const float*)d_in[9];
  const float* Wo = (const float*)d_in[10];
  const float* bo = (const float*)d_in[11];
  float* out = (float*)d_out;

  char* ws = (char*)d_ws;
  bf16* qb  = (bf16*)(ws + 0);          // 4096x1024   [0, 8388608)
  bf16* att = qb;                       // alias (qb dead after gemm-Q)
  bf16* kb  = (bf16*)(ws + 8388608);    // 8192x768 (dead after gemm_qkv)
  float* Wp = (float*)(ws + 8388608);   // 1024x128 f32 = 512KB (over dead kb)
  bf16* vb  = (bf16*)(ws + 20971520);   // 8192x768
  bf16* vT  = (bf16*)(ws + 16777216);   // [B][H][64][2048] alias over kb tail
  bf16* WqT = (bf16*)(ws + 33554432);
  bf16* WkT = (bf16*)(ws + 35651584);
  bf16* WvT = (bf16*)(ws + 37224448);
  bf16* WoT = (bf16*)(ws + 38797312);
  bf16* qp  = (bf16*)(ws + 40894464);
  bf16* kp  = (bf16*)(ws + 49283072);
  bf16* vp  = (bf16*)(ws + 66060288);   // dead after vtrans
  _Float16* Op = (_Float16*)(ws + 66060288);  // 2x512x128x64 fp16 = 16MB
  float* mf = (float*)(ws + 82837504);  // 8192 floats

  mask_prep<<<32, 256, 0, stream>>>(mask_raw, mf, B_ * LKV_);

  cvt3<<<dim3(6144, 3), 256, 0, stream>>>(query, key, value, qb, kb, vb);

  wtrans4<<<dim3(16, 16, 4), 256, 0, stream>>>(Wq, Wk, Wv, Wo,
                                               WqT, WkT, WvT, WoT);

  gemm_qkv<<<dim3(8, 64, 3), 256, 0, stream>>>(qb, kb, vb, WqT, WkT, WvT,
                                               bq, bk, bv, qp, kp, vp);

  vtrans<<<dim3(32, 16, 4), 256, 0, stream>>>(vp, vT);

  attn6<<<1024, 256, 0, stream>>>(qp, kp, vT, mf, Op, Wp);

  attn_combine<<<512, 256, 0, stream>>>(Op, Wp, att);

  gemm_bt<0><<<dim3(8, 32), 256, 0, stream>>>(att, WoT, bo, out,
                                              B_ * LQ_, ODIM_, ODIM_);
}